// Round 13
// baseline (716.634 us; speedup 1.0000x reference)
//
#include <hip/hip_runtime.h>
#include <hip/hip_bf16.h>

using bf16 = __bf16;
typedef __bf16 bf16x8 __attribute__((ext_vector_type(8)));
typedef __bf16 bf16x4 __attribute__((ext_vector_type(4)));
typedef float  f32x4  __attribute__((ext_vector_type(4)));
typedef float  f32x16 __attribute__((ext_vector_type(16)));

#define MFMA32(a, b, c) __builtin_amdgcn_mfma_f32_32x32x16_bf16((a), (b), (c), 0, 0, 0)

// packed weight layout for 32x32x16 A-fragments (bf16 elem offsets in d_ws):
// element j of lane L -> W[kt*16 + (L>>5)*8 + j][nt*32 + (L&31)], zero-padded.
constexpr int P0  = 0;        // 64x256
constexpr int P1  = 16384;    // 256x256
constexpr int P2  = 81920;
constexpr int P3  = 147456;
constexpr int P4  = 212992;
constexpr int P5  = 278528;   // 320x256
constexpr int P6  = 360448;
constexpr int P7  = 425984;
constexpr int PD  = 491520;   // 256x32
constexpr int PC0 = 499712;   // 288x128
constexpr int PC1 = 536576;   // 128x32

constexpr int NPTS = 4096 * 128;
constexpr int MT = 128;        // points per block
constexpr int PTILES = MT / 32;
constexpr int SH = 320;        // 40 chunks of 8 bf16 (16B)

// H layout: (row p, col c): chunks 0..31 (cols 0..255) at chunk ^ (p&15);
// chunks 32..39 (cols 256..319, encodings) at chunk ^ (p&7). Bijective per
// row per region; spreads ds_read_b128 bank groups for 32-point fragments.

// ------------------------------- pack kernel -------------------------------
struct PackArgs {
    const float* src[11];
    int K[11], N[11], Ntiles[11], tasks[11], dstoff[11];
};

__global__ void nerf_pack(PackArgs pa, bf16* __restrict__ dst) {
    int idx = blockIdx.x * 256 + threadIdx.x;
    for (int l = 0; l < 11; ++l) {
        if (idx < pa.tasks[l]) {
            const int lane = idx & 63;
            const int blk  = idx >> 6;
            const int nt   = blk % pa.Ntiles[l];
            const int kt   = blk / pa.Ntiles[l];
            const int kb   = kt * 16 + ((lane >> 5) << 3);
            const int n    = nt * 32 + (lane & 31);
            const float* s = pa.src[l];
            const int K = pa.K[l], N = pa.N[l];
            bf16x8 v;
#pragma unroll
            for (int j = 0; j < 8; ++j) {
                int k = kb + j;
                v[j] = (bf16)((k < K && n < N) ? s[(size_t)k * N + n] : 0.f);
            }
            *(bf16x8*)(dst + pa.dstoff[l] + (size_t)idx * 8) = v;
            return;
        }
        idx -= pa.tasks[l];
    }
}

// ------------------------------- layer -------------------------------------
// Block = 512 threads = 8 waves, M=128 (4 point tiles of 32).
// D[m=chan][n=point] via mfma_32x32x16: C/D col=lane&31, row=(r&3)+8*(r>>2)+4*(lane>>5).
// N=256: CG=4 chan groups (NT_W=2), NPG=2 (PT_W=2) — weights 2x/block, af 4x.
template <int KP, int N, bool RELU, int MODE, bool HAZARD, int COFF>
__device__ __forceinline__ void layer(bf16* H,
                                      const bf16* __restrict__ wp,
                                      const float* __restrict__ bias,
                                      float* __restrict__ gout, int m0) {
    constexpr int NTILES = N / 32;
    constexpr int NT_W   = (NTILES >= 2) ? 2 : 1;
    constexpr int CG     = NTILES / NT_W;            // chan wave-groups
    constexpr int NPG    = 8 / CG;                   // point wave-groups
    constexpr int PT_W   = (PTILES + NPG - 1) / NPG; // point tiles per wave
    constexpr int CB     = COFF >> 3;                // base chunk

    const int tid  = threadIdx.x;
    const int lane = tid & 63;
    const int w    = tid >> 6;
    const int l31  = lane & 31;
    const int hi   = lane >> 5;                      // q5
    const int nt0  = (w % CG) * NT_W;
    const int pt0  = (w / CG) * PT_W;
    const int s15  = l31 & 15, s7 = l31 & 7;

    f32x16 acc[PT_W][NT_W];
    // bias folded into acc init: reg r <-> chan (nt0+nt)*32 + (r&3)+8*(r>>2)+4*hi
    if constexpr (MODE == 0) {
#pragma unroll
        for (int nt = 0; nt < NT_W; ++nt) {
#pragma unroll
            for (int g = 0; g < 4; ++g) {
                f32x4 b4 = *(const f32x4*)(bias + (nt0 + nt) * 32 + g * 8 + hi * 4);
#pragma unroll
                for (int pt = 0; pt < PT_W; ++pt) {
                    acc[pt][nt][g * 4 + 0] = b4[0];
                    acc[pt][nt][g * 4 + 1] = b4[1];
                    acc[pt][nt][g * 4 + 2] = b4[2];
                    acc[pt][nt][g * 4 + 3] = b4[3];
                }
            }
        }
    } else {
#pragma unroll
        for (int pt = 0; pt < PT_W; ++pt)
#pragma unroll
            for (int r = 0; r < 16; ++r) {
                const int chan = (r & 3) + 8 * (r >> 2) + 4 * hi;
                float bv = 0.f;
                if (MODE == 1) bv = (chan == 0) ? bias[0] : 0.f;
                else           bv = (chan < 3) ? bias[chan] : 0.f;
                acc[pt][0][r] = bv;
            }
    }

#pragma unroll 4
    for (int kt = 0; kt < KP / 16; ++kt) {
        bf16x8 wf[NT_W];
#pragma unroll
        for (int nt = 0; nt < NT_W; ++nt)
            wf[nt] = *(const bf16x8*)(wp + ((size_t)(kt * NTILES + nt0 + nt) * 64 + lane) * 8);
        const int c = CB + kt * 2 + hi;                       // logical chunk
        const int swz = (CB + kt * 2 < 32) ? s15 : s7;        // region mask
#pragma unroll
        for (int pt = 0; pt < PT_W; ++pt) {
            if (pt0 + pt < PTILES) {
                const int point = (pt0 + pt) * 32 + l31;
                bf16x8 af = *(const bf16x8*)(H + point * SH + ((c ^ swz) << 3));
#pragma unroll
                for (int nt = 0; nt < NT_W; ++nt)
                    acc[pt][nt] = MFMA32(wf[nt], af, acc[pt][nt]);
            }
        }
    }
    if (HAZARD) __syncthreads();   // all in-place reads done before writes

    if constexpr (MODE == 0) {
#pragma unroll
        for (int pt = 0; pt < PT_W; ++pt) {
            const int point = (pt0 + pt) * 32 + l31;
#pragma unroll
            for (int nt = 0; nt < NT_W; ++nt) {
#pragma unroll
                for (int g = 0; g < 4; ++g) {
                    bf16x4 o;
#pragma unroll
                    for (int r = 0; r < 4; ++r) {
                        float v = acc[pt][nt][g * 4 + r];
                        if (RELU) v = v > 0.f ? v : 0.f;
                        o[r] = (bf16)v;
                    }
                    const int chunk = (nt0 + nt) * 4 + g;
                    *(bf16x4*)(H + point * SH + ((chunk ^ s15) << 3) + hi * 4) = o;
                }
            }
        }
        __syncthreads();           // writes visible before next layer reads
    } else if constexpr (MODE == 1) {
        if (hi == 0 && pt0 < PTILES)
            gout[m0 + pt0 * 32 + l31] = acc[0][0][0];
    } else {
        if (hi == 0 && pt0 < PTILES) {
            const size_t p3 = (size_t)(m0 + pt0 * 32 + l31) * 3;
            gout[p3 + 0] = acc[0][0][0];
            gout[p3 + 1] = acc[0][0][1];
            gout[p3 + 2] = acc[0][0][2];
        }
    }
}

// ------------------------------- main kernel -------------------------------
__global__ __launch_bounds__(512, 4)
void nerf_main(const float* __restrict__ pos, const float* __restrict__ dir,
               const float* __restrict__ b0, const float* __restrict__ b1,
               const float* __restrict__ b2, const float* __restrict__ b3,
               const float* __restrict__ b4, const float* __restrict__ b5,
               const float* __restrict__ b6, const float* __restrict__ b7,
               const float* __restrict__ bd, const float* __restrict__ bc0,
               const float* __restrict__ bc1,
               const bf16* __restrict__ wpk, float* __restrict__ out) {
    __shared__ __align__(16) bf16 H[MT * SH];   // 81920 B -> 2 blocks/CU

    const int m0 = blockIdx.x * MT;
    const int tid = threadIdx.x;

    // positional encoding -> cols 256..315; 316..319 zeroed (K-pad).
    // chunks 32..39, swizzle ^ (row&7). 4 threads/row, 2 chunks each.
    {
        const int row = tid >> 2;          // 0..127
        const int sub = tid & 3;
        const int swz = row & 7;
        const size_t pb = (size_t)(m0 + row) * 3;
        float xs[3] = { pos[pb], pos[pb + 1], pos[pb + 2] };
#pragma unroll
        for (int h = 0; h < 2; ++h) {
            const int chunk = 32 + sub * 2 + h;
            bf16* dst = H + row * SH + ((chunk ^ swz) << 3);
#pragma unroll
            for (int j = 0; j < 8; ++j) {
                const int col = sub * 16 + h * 8 + j;   // 0..63
                float v = 0.f;
                if (col < 60) {
                    const int c = col / 20, rem = col % 20, s = rem / 10, i = rem % 10;
                    const float arg = xs[c] * (float)(1 << i);
                    v = s ? __cosf(arg) : __sinf(arg);
                }
                dst[j] = (bf16)v;
            }
        }
    }
    __syncthreads();

    // trunk, in-place; embed_pos lives in cols 256..315 until L5 consumes it
    layer<64,  256, true, 0, false, 256>(H, wpk + P0, b0, nullptr, m0);
    layer<256, 256, true, 0, true,  0  >(H, wpk + P1, b1, nullptr, m0);
    layer<256, 256, true, 0, true,  0  >(H, wpk + P2, b2, nullptr, m0);
    layer<256, 256, true, 0, true,  0  >(H, wpk + P3, b3, nullptr, m0);
    layer<256, 256, true, 0, true,  0  >(H, wpk + P4, b4, nullptr, m0);
    layer<320, 256, true, 0, true,  0  >(H, wpk + P5, b5, nullptr, m0);  // skip concat
    layer<256, 256, true, 0, true,  0  >(H, wpk + P6, b6, nullptr, m0);
    layer<256, 256, true, 0, true,  0  >(H, wpk + P7, b7, nullptr, m0);  // h8 -> cols 0..255

    // density head: reads chunks 0..31, writes global only
    layer<256, 32, false, 1, false, 0>(H, wpk + PD, bd, out, m0);

    // dir encoding -> cols 256..279; 280..287 zeroed (c0 K-pad); chunks 32..35
    // disjoint from density's reads -> no barrier before.
    {
        const int row = tid >> 2;
        const int sub = tid & 3;
        const int swz = row & 7;
        const size_t db = (size_t)(m0 + row) * 3;
        float ds[3] = { dir[db], dir[db + 1], dir[db + 2] };
        const int chunk = 32 + sub;
        bf16* dst = H + row * SH + ((chunk ^ swz) << 3);
#pragma unroll
        for (int j = 0; j < 8; ++j) {
            const int col = sub * 8 + j;   // 0..31
            float v = 0.f;
            if (col < 24) {
                const int c = col / 8, rem = col % 8, s = rem / 4, i = rem % 4;
                const float arg = ds[c] * (float)(1 << i);
                v = s ? __cosf(arg) : __sinf(arg);
            }
            dst[j] = (bf16)v;
        }
    }
    __syncthreads();

    // color head
    layer<288, 128, true, 0, true,  0>(H, wpk + PC0, bc0, nullptr, m0); // c0 -> cols 0..127
    layer<128, 32, false, 2, false, 0>(H, wpk + PC1, bc1, out + NPTS, m0);
}

// Loud sentinel if harness I/O layout differs from expectation.
__global__ void nerf_sentinel(float* __restrict__ out, float val) {
    if (threadIdx.x == 0 && blockIdx.x == 0) out[0] = val;
}

// ------------------------------- launcher ----------------------------------
extern "C" void kernel_launch(void* const* d_in, const int* in_sizes, int n_in,
                              void* d_out, int out_size, void* d_ws, size_t ws_size,
                              hipStream_t stream) {
    static const int exp2[24] = {
        1572864, 1572864,
        15360, 256, 65536, 256, 65536, 256, 65536, 256,
        65536, 256, 80896, 256, 65536, 256, 65536, 256,
        256, 1, 35840, 128, 384, 3
    };
    int bad = -1;
    if (n_in != 24) bad = 99;
    else {
        for (int i = 0; i < 24; ++i)
            if (in_sizes[i] != exp2[i]) { bad = i; break; }
    }
    if (bad < 0 && out_size != NPTS * 4) bad = 97;
    if (bad >= 0) {
        nerf_sentinel<<<1, 64, 0, stream>>>((float*)d_out, 20000.f + 100.f * bad);
        return;
    }

    static const int wi[11] = {2, 4, 6, 8, 10, 12, 14, 16, 18, 20, 22};
    static const int Ks[11] = {60, 256, 256, 256, 256, 316, 256, 256, 256, 280, 128};
    static const int Ns[11] = {256, 256, 256, 256, 256, 256, 256, 256, 1, 128, 3};
    static const int Kp[11] = {64, 256, 256, 256, 256, 320, 256, 256, 256, 288, 128};
    static const int Np[11] = {256, 256, 256, 256, 256, 256, 256, 256, 32, 128, 32};

    PackArgs pa;
    int off = 0, total_tasks = 0;
    for (int l = 0; l < 11; ++l) {
        pa.src[l]    = (const float*)d_in[wi[l]];
        pa.K[l]      = Ks[l];
        pa.N[l]      = Ns[l];
        pa.Ntiles[l] = Np[l] / 32;
        pa.tasks[l]  = (Kp[l] / 16) * (Np[l] / 32) * 64;
        pa.dstoff[l] = off;
        off += pa.tasks[l] * 8;
        total_tasks += pa.tasks[l];
    }
    bf16* wpk = (bf16*)d_ws;

    nerf_pack<<<(total_tasks + 255) / 256, 256, 0, stream>>>(pa, wpk);

    nerf_main<<<NPTS / MT, 512, 0, stream>>>(
        (const float*)d_in[0], (const float*)d_in[1],
        (const float*)d_in[3], (const float*)d_in[5], (const float*)d_in[7],
        (const float*)d_in[9], (const float*)d_in[11], (const float*)d_in[13],
        (const float*)d_in[15], (const float*)d_in[17], (const float*)d_in[19],
        (const float*)d_in[21], (const float*)d_in[23],
        wpk, (float*)d_out);
}